// Round 1
// baseline (852.898 us; speedup 1.0000x reference)
//
#include <hip/hip_runtime.h>
#include <hip/hip_bf16.h>

// BahdanauAttention: B=32, S=2048, H=512, D2=1024
// Pipeline: memset -> cvt_ua(bf16) -> qw -> score_gemm(MFMA bf16) -> softmax -> context

typedef __attribute__((ext_vector_type(8))) short bf16x8;
typedef __attribute__((ext_vector_type(4))) float f32x4;

__device__ __forceinline__ unsigned pk_bf16(float x, float y) {
  union { __hip_bfloat162 h; unsigned u; } c;
  c.h = __float22bfloat162_rn(make_float2(x, y));
  return c.u;
}

__device__ __forceinline__ float fast_tanh(float x) {
  // tanh(x) = 1 - 2/(exp(2x)+1); exact limits at +-inf, ~1e-7 abs error
  float e = __expf(2.0f * x);
  return 1.0f - 2.0f / (e + 1.0f);
}

// ---- convert Ua_w (1024x1024 fp32) -> bf16 workspace ----
__global__ __launch_bounds__(256) void k_cvt_ua(const float4* __restrict__ src,
                                                uint2* __restrict__ dst) {
  int i = blockIdx.x * 256 + threadIdx.x;   // 1024 blocks -> 1M/4 chunks
  float4 v = src[i];
  uint2 o;
  o.x = pk_bf16(v.x, v.y);
  o.y = pk_bf16(v.z, v.w);
  dst[i] = o;
}

// ---- qW[b][j] = sum_k q_cat[b][k]*Wa_w[j][k] (+ Wa_b + Ua_b on kc==0) ----
// grid (4 k-chunks, 32 batches); wave-per-j, lane-split-k, coalesced Wa reads.
__global__ __launch_bounds__(256) void k_qw(const float* __restrict__ query,
                                            const float* __restrict__ Wa_w,
                                            const float* __restrict__ Wa_b,
                                            const float* __restrict__ Ua_b,
                                            float* __restrict__ qW) {
  const int kc = blockIdx.x;   // 0..3
  const int b  = blockIdx.y;   // 0..31
  const int t  = threadIdx.x;
  __shared__ float qloc[256];
  {
    int k = kc * 256 + t;
    // q_cat = concat(query[b,1,:], query[b,3,:]); query is (B,4,512)
    qloc[t] = (k < 512) ? query[b * 2048 + 512 + k]
                        : query[b * 2048 + 1536 + (k - 512)];
  }
  __syncthreads();
  const int w = t >> 6, lane = t & 63;
  const float4 q4 = *(const float4*)(qloc + lane * 4);
  for (int j = w; j < 1024; j += 4) {
    const float4 wa = *(const float4*)(Wa_w + j * 1024 + kc * 256 + lane * 4);
    float s = wa.x * q4.x + wa.y * q4.y + wa.z * q4.z + wa.w * q4.w;
    #pragma unroll
    for (int off = 1; off < 64; off <<= 1) s += __shfl_xor(s, off);
    if (lane == 0) {
      if (kc == 0) s += Wa_b[j] + Ua_b[j];
      atomicAdd(&qW[b * 1024 + j], s);
    }
  }
}

// ---- scores[r] = sum_j Va[j] * tanh( (keys@Ua^T)[r][j] + qW[b][j] ) ----
// 128x128 tile, BK=64, 4 waves (2x2), 4x4 mfma_f32_16x16x32_bf16 per wave.
// LDS row stride 72 bf16 (144B = 9*16B): 16B-aligned b128 frag reads, 2-way max bank alias.
__global__ __launch_bounds__(256) void k_score(const float* __restrict__ keys,
                                               const unsigned short* __restrict__ Uab,
                                               const float* __restrict__ qW,
                                               const float* __restrict__ Va,
                                               float* __restrict__ scores) {
  __shared__ __align__(16) unsigned short As[128 * 72];
  __shared__ __align__(16) unsigned short Bs[128 * 72];
  const int jblk = blockIdx.x;   // 0..7   (j fast: 8 sibling blocks share keys rows -> LLC)
  const int rblk = blockIdx.y;   // 0..511
  const int t = threadIdx.x;
  const int lane = t & 63, w = t >> 6;
  const int wm = w >> 1, wn = w & 1;
  const int l15 = lane & 15, quad = lane >> 4;
  const int row0 = rblk * 128;
  const int j0 = jblk * 128;

  f32x4 acc[4][4];
  #pragma unroll
  for (int i = 0; i < 4; i++)
    #pragma unroll
    for (int j = 0; j < 4; j++) acc[i][j] = (f32x4){0.f, 0.f, 0.f, 0.f};

  for (int k0 = 0; k0 < 1024; k0 += 64) {
    __syncthreads();
    // stage A: keys 128x64 fp32 -> bf16 LDS  (coalesced float4, cvt_pk, ds_write_b64)
    #pragma unroll
    for (int i = 0; i < 8; ++i) {
      int c = i * 256 + t;
      int m = c >> 4, f4 = c & 15;
      float4 v = *(const float4*)(keys + (row0 + m) * 1024 + k0 + f4 * 4);
      uint2 p;
      p.x = pk_bf16(v.x, v.y);
      p.y = pk_bf16(v.z, v.w);
      *(uint2*)(As + m * 72 + f4 * 4) = p;
    }
    // stage B: Ua bf16 128x64 (16B chunks, ds_write_b128)
    #pragma unroll
    for (int i = 0; i < 4; ++i) {
      int c = i * 256 + t;
      int j = c >> 3, k8 = c & 7;
      uint4 v = *(const uint4*)(Uab + (j0 + j) * 1024 + k0 + k8 * 8);
      *(uint4*)(Bs + j * 72 + k8 * 8) = v;
    }
    __syncthreads();
    #pragma unroll
    for (int ks = 0; ks < 2; ++ks) {
      bf16x8 af[4], bfr[4];
      #pragma unroll
      for (int i = 0; i < 4; i++)
        af[i] = *(const bf16x8*)(As + (wm * 64 + i * 16 + l15) * 72 + ks * 32 + quad * 8);
      #pragma unroll
      for (int i = 0; i < 4; i++)
        bfr[i] = *(const bf16x8*)(Bs + (wn * 64 + i * 16 + l15) * 72 + ks * 32 + quad * 8);
      #pragma unroll
      for (int i = 0; i < 4; i++)
        #pragma unroll
        for (int j = 0; j < 4; j++)
          acc[i][j] = __builtin_amdgcn_mfma_f32_16x16x32_bf16(af[i], bfr[j], acc[i][j], 0, 0, 0);
    }
  }

  // epilogue: tanh(e + qW) dot Va, reduce 16 cols/lane-group, atomicAdd per row.
  // (Va_b omitted: softmax is shift-invariant.)
  const int b = row0 >> 11;   // 2048 rows per batch, 128 | 2048 -> constant per block
  float va[4], qb[4];
  #pragma unroll
  for (int j = 0; j < 4; j++) {
    int jg = j0 + wn * 64 + j * 16 + l15;
    va[j] = Va[jg];
    qb[j] = qW[b * 1024 + jg];
  }
  #pragma unroll
  for (int i = 0; i < 4; i++) {
    #pragma unroll
    for (int r = 0; r < 4; r++) {
      float s = 0.f;
      #pragma unroll
      for (int j = 0; j < 4; j++)
        s += va[j] * fast_tanh(acc[i][j][r] + qb[j]);
      s += __shfl_xor(s, 1);
      s += __shfl_xor(s, 2);
      s += __shfl_xor(s, 4);
      s += __shfl_xor(s, 8);
      if (l15 == 0) {
        int rg = row0 + wm * 64 + i * 16 + quad * 4 + r;   // C/D: row = quad*4+reg
        atomicAdd(&scores[rg], s);
      }
    }
  }
}

// ---- softmax over S=2048 per batch -> weights (output 1) ----
__global__ __launch_bounds__(256) void k_softmax(const float* __restrict__ scores,
                                                 float* __restrict__ wout) {
  const int b = blockIdx.x, t = threadIdx.x;
  const int lane = t & 63, w = t >> 6;
  __shared__ float red[4];
  float v[8];
  float mx = -1e30f;
  #pragma unroll
  for (int i = 0; i < 8; i++) {
    v[i] = scores[b * 2048 + i * 256 + t];
    mx = fmaxf(mx, v[i]);
  }
  #pragma unroll
  for (int off = 1; off < 64; off <<= 1) mx = fmaxf(mx, __shfl_xor(mx, off));
  if (lane == 0) red[w] = mx;
  __syncthreads();
  mx = fmaxf(fmaxf(red[0], red[1]), fmaxf(red[2], red[3]));
  float sum = 0.f;
  #pragma unroll
  for (int i = 0; i < 8; i++) {
    v[i] = __expf(v[i] - mx);
    sum += v[i];
  }
  #pragma unroll
  for (int off = 1; off < 64; off <<= 1) sum += __shfl_xor(sum, off);
  __syncthreads();
  if (lane == 0) red[w] = sum;
  __syncthreads();
  sum = red[0] + red[1] + red[2] + red[3];
  float inv = 1.0f / sum;
  #pragma unroll
  for (int i = 0; i < 8; i++) wout[b * 2048 + i * 256 + t] = v[i] * inv;
}

// ---- context[b][d] = sum_s w[b][s]*keys[b][s][d]  (fp32, HBM-bound) ----
__global__ __launch_bounds__(256) void k_context(const float* __restrict__ keys,
                                                 const float* __restrict__ wts,
                                                 float* __restrict__ ctx) {
  const int sc = blockIdx.x;   // 0..15 (128 s each)
  const int b  = blockIdx.y;   // 0..31
  const int t  = threadIdx.x;
  __shared__ float wl[128];
  if (t < 128) wl[t] = wts[b * 2048 + sc * 128 + t];
  __syncthreads();
  const float4* kp = (const float4*)(keys + ((size_t)(b * 2048 + sc * 128) << 10)) + t;
  float4 a = {0.f, 0.f, 0.f, 0.f};
  #pragma unroll 4
  for (int s = 0; s < 128; ++s) {
    float4 kv = kp[s * 256];
    float wv = wl[s];
    a.x += wv * kv.x; a.y += wv * kv.y; a.z += wv * kv.z; a.w += wv * kv.w;
  }
  float* o = ctx + b * 1024 + t * 4;
  atomicAdd(o + 0, a.x);
  atomicAdd(o + 1, a.y);
  atomicAdd(o + 2, a.z);
  atomicAdd(o + 3, a.w);
}

extern "C" void kernel_launch(void* const* d_in, const int* in_sizes, int n_in,
                              void* d_out, int out_size, void* d_ws, size_t ws_size,
                              hipStream_t stream) {
  const float* query = (const float*)d_in[0];
  const float* keys  = (const float*)d_in[1];
  const float* Wa_w  = (const float*)d_in[2];
  const float* Wa_b  = (const float*)d_in[3];
  const float* Ua_w  = (const float*)d_in[4];
  const float* Ua_b  = (const float*)d_in[5];
  const float* Va_w  = (const float*)d_in[6];
  // d_in[7] = Va_b: unused (softmax shift-invariance)

  // workspace layout (2.4 MB): scores[65536] f32 | qW[32768] f32 | Uab[1M] bf16
  float* scores = (float*)d_ws;
  float* qW     = scores + 65536;
  unsigned short* Uab = (unsigned short*)(qW + 32768);

  float* ctx = (float*)d_out;        // context: 32*1024
  float* wts = ctx + 32768;          // weights: 32*2048

  hipMemsetAsync(scores, 0, (65536 + 32768) * sizeof(float), stream);  // atomic targets
  hipMemsetAsync(ctx, 0, 32768 * sizeof(float), stream);

  k_cvt_ua<<<1024, 256, 0, stream>>>((const float4*)Ua_w, (uint2*)Uab);
  k_qw<<<dim3(4, 32), 256, 0, stream>>>(query, Wa_w, Wa_b, Ua_b, qW);
  k_score<<<dim3(8, 512), 256, 0, stream>>>(keys, Uab, qW, Va_w, scores);
  k_softmax<<<32, 256, 0, stream>>>(scores, wts);
  k_context<<<dim3(16, 32), 256, 0, stream>>>(keys, wts, ctx);
}

// Round 2
// 622.476 us; speedup vs baseline: 1.3702x; 1.3702x over previous
//
#include <hip/hip_runtime.h>
#include <hip/hip_bf16.h>

// BahdanauAttention: B=32, S=2048, H=512, D2=1024
// Path A (ws >= 137MB): cvt keys+Ua -> bf16 ws; score GEMM with global_load_lds
// staging + XOR-swizzled LDS (conflict-free, async). Fallback: round-1 score.

typedef __attribute__((ext_vector_type(8))) short bf16x8;
typedef __attribute__((ext_vector_type(4))) float f32x4;

__device__ __forceinline__ unsigned pk_bf16(float x, float y) {
  union { __hip_bfloat162 h; unsigned u; } c;
  c.h = __float22bfloat162_rn(make_float2(x, y));
  return c.u;
}

__device__ __forceinline__ float fast_tanh(float x) {
  float e = __expf(2.0f * x);
  return 1.0f - 2.0f / (e + 1.0f);
}

// async global->LDS, 16B per lane; LDS dest = wave-uniform base + lane*16
typedef const __attribute__((address_space(1))) void* gas_t;
typedef __attribute__((address_space(3))) void* las_t;
__device__ __forceinline__ void ld_lds16(const void* g, void* l) {
  __builtin_amdgcn_global_load_lds((gas_t)g, (las_t)l, 16, 0, 0);
}

// ---- fp32 -> bf16 bulk convert (2 float4 -> 1 uint4 per thread) ----
__global__ __launch_bounds__(256) void k_cvt(const float4* __restrict__ src,
                                             uint4* __restrict__ dst) {
  int i = blockIdx.x * 256 + threadIdx.x;
  float4 a = src[2 * i], b = src[2 * i + 1];
  uint4 o;
  o.x = pk_bf16(a.x, a.y);
  o.y = pk_bf16(a.z, a.w);
  o.z = pk_bf16(b.x, b.y);
  o.w = pk_bf16(b.z, b.w);
  dst[i] = o;
}

// ---- qW[b][j] = q_cat[b]·Wa_w[j] + Wa_b[j] + Ua_b[j] ----
// grid (32 j-chunks, 32 b); 8 lanes split K=1024; no atomics.
__global__ __launch_bounds__(256) void k_qw(const float* __restrict__ query,
                                            const float* __restrict__ Wa_w,
                                            const float* __restrict__ Wa_b,
                                            const float* __restrict__ Ua_b,
                                            float* __restrict__ qW) {
  const int jc = blockIdx.x, b = blockIdx.y, t = threadIdx.x;
  __shared__ float4 qloc[256];
  {
    // q_cat = concat(query[b,1,:], query[b,3,:]); query is (B,4,512)
    const float* base = (t < 128) ? (query + b * 2048 + 512) : (query + b * 2048 + 1536 - 512);
    qloc[t] = *(const float4*)(base + t * 4);
  }
  __syncthreads();
  const int jl = t >> 3, ks = t & 7;
  const int j = jc * 32 + jl;
  const float* wrow = Wa_w + j * 1024;
  float s = 0.f;
  #pragma unroll
  for (int i = 0; i < 32; ++i) {
    float4 wv = *(const float4*)(wrow + i * 32 + ks * 4);
    float4 q4 = qloc[i * 8 + ks];
    s += wv.x * q4.x + wv.y * q4.y + wv.z * q4.z + wv.w * q4.w;
  }
  s += __shfl_xor(s, 1);
  s += __shfl_xor(s, 2);
  s += __shfl_xor(s, 4);
  if (ks == 0) qW[b * 1024 + j] = s + Wa_b[j] + Ua_b[j];
}

// ---- PATH A score: keys16(bf16) @ Uab^T -> tanh -> ·Va -> scores ----
// 128x128 tile, BK=64, global_load_lds staging, XOR-swizzled unpadded LDS.
__global__ __launch_bounds__(256) void k_score2(const unsigned short* __restrict__ keys16,
                                                const unsigned short* __restrict__ Uab,
                                                const float* __restrict__ qW,
                                                const float* __restrict__ Va,
                                                float* __restrict__ scores) {
  __shared__ __align__(16) unsigned short As[128 * 64];  // 16 KB
  __shared__ __align__(16) unsigned short Bs[128 * 64];  // 16 KB
  const int jblk = blockIdx.x;   // 0..7 (fast: siblings share keys rows -> LLC)
  const int rblk = blockIdx.y;   // 0..511
  const int t = threadIdx.x;
  const int lane = t & 63, w = t >> 6;
  const int wm = w >> 1, wn = w & 1;
  const int l15 = lane & 15, quad = lane >> 4;
  const int row0 = rblk * 128, j0 = jblk * 128;
  // staging geometry: chunk = 1KB = 8 rows x 128B; lane -> (row lr, 16B slot)
  const int lr = lane >> 3;                 // row-in-chunk 0..7 (== row&7)
  const int sg = (lane & 7) ^ lr;           // swizzled global 16B-slot index

  f32x4 acc[4][4];
  #pragma unroll
  for (int i = 0; i < 4; i++)
    #pragma unroll
    for (int j = 0; j < 4; j++) acc[i][j] = (f32x4){0.f, 0.f, 0.f, 0.f};

  const int rb = l15 & 7;   // frag-row & 7 (i*16, wm*64 are multiples of 8)
  const int aoff = (wm * 64 + l15) * 64;
  const int boff = (wn * 64 + l15) * 64;

  for (int k0 = 0; k0 < 1024; k0 += 64) {
    if (k0) __syncthreads();   // prior ds_reads done before overwrite
    #pragma unroll
    for (int i = 0; i < 4; ++i) {
      const int c = w * 4 + i;             // chunk 0..15
      const int row = c * 8 + lr;
      ld_lds16(keys16 + (size_t)(row0 + row) * 1024 + k0 + sg * 8, As + c * 512);
      ld_lds16(Uab + (size_t)(j0 + row) * 1024 + k0 + sg * 8, Bs + c * 512);
    }
    __syncthreads();           // drains vmcnt(0): tiles resident
    #pragma unroll
    for (int ks = 0; ks < 2; ++ks) {
      const int x = ((ks * 4 + quad) ^ rb) * 8;   // swizzled frag slot
      bf16x8 af[4], bfr[4];
      #pragma unroll
      for (int i = 0; i < 4; i++) af[i] = *(const bf16x8*)(As + aoff + i * 1024 + x);
      #pragma unroll
      for (int i = 0; i < 4; i++) bfr[i] = *(const bf16x8*)(Bs + boff + i * 1024 + x);
      #pragma unroll
      for (int i = 0; i < 4; i++)
        #pragma unroll
        for (int j = 0; j < 4; j++)
          acc[i][j] = __builtin_amdgcn_mfma_f32_16x16x32_bf16(af[i], bfr[j], acc[i][j], 0, 0, 0);
    }
  }

  // epilogue: scores[r] += sum_j Va[j]*tanh(acc + qW[b][j]); Va_b dropped (softmax shift-inv)
  const int b = row0 >> 11;
  float va[4], qb[4];
  #pragma unroll
  for (int j = 0; j < 4; j++) {
    int jg = j0 + wn * 64 + j * 16 + l15;
    va[j] = Va[jg];
    qb[j] = qW[b * 1024 + jg];
  }
  #pragma unroll
  for (int i = 0; i < 4; i++) {
    #pragma unroll
    for (int r = 0; r < 4; r++) {
      float s = 0.f;
      #pragma unroll
      for (int j = 0; j < 4; j++)
        s += va[j] * fast_tanh(acc[i][j][r] + qb[j]);
      s += __shfl_xor(s, 1);
      s += __shfl_xor(s, 2);
      s += __shfl_xor(s, 4);
      s += __shfl_xor(s, 8);
      if (l15 == 0) {
        int rg = row0 + wm * 64 + i * 16 + quad * 4 + r;   // C/D: row = quad*4+reg
        atomicAdd(&scores[rg], s);
      }
    }
  }
}

// ---- FALLBACK score (round-1, fp32 keys in-kernel cvt) ----
__global__ __launch_bounds__(256) void k_score1(const float* __restrict__ keys,
                                                const unsigned short* __restrict__ Uab,
                                                const float* __restrict__ qW,
                                                const float* __restrict__ Va,
                                                float* __restrict__ scores) {
  __shared__ __align__(16) unsigned short As[128 * 72];
  __shared__ __align__(16) unsigned short Bs[128 * 72];
  const int jblk = blockIdx.x, rblk = blockIdx.y;
  const int t = threadIdx.x;
  const int lane = t & 63, w = t >> 6;
  const int wm = w >> 1, wn = w & 1;
  const int l15 = lane & 15, quad = lane >> 4;
  const int row0 = rblk * 128, j0 = jblk * 128;
  f32x4 acc[4][4];
  #pragma unroll
  for (int i = 0; i < 4; i++)
    #pragma unroll
    for (int j = 0; j < 4; j++) acc[i][j] = (f32x4){0.f, 0.f, 0.f, 0.f};
  for (int k0 = 0; k0 < 1024; k0 += 64) {
    __syncthreads();
    #pragma unroll
    for (int i = 0; i < 8; ++i) {
      int c = i * 256 + t, m = c >> 4, f4 = c & 15;
      float4 v = *(const float4*)(keys + (size_t)(row0 + m) * 1024 + k0 + f4 * 4);
      uint2 p;
      p.x = pk_bf16(v.x, v.y);
      p.y = pk_bf16(v.z, v.w);
      *(uint2*)(As + m * 72 + f4 * 4) = p;
    }
    #pragma unroll
    for (int i = 0; i < 4; ++i) {
      int c = i * 256 + t, j = c >> 3, k8 = c & 7;
      *(uint4*)(Bs + j * 72 + k8 * 8) = *(const uint4*)(Uab + (size_t)(j0 + j) * 1024 + k0 + k8 * 8);
    }
    __syncthreads();
    #pragma unroll
    for (int ks = 0; ks < 2; ++ks) {
      bf16x8 af[4], bfr[4];
      #pragma unroll
      for (int i = 0; i < 4; i++)
        af[i] = *(const bf16x8*)(As + (wm * 64 + i * 16 + l15) * 72 + ks * 32 + quad * 8);
      #pragma unroll
      for (int i = 0; i < 4; i++)
        bfr[i] = *(const bf16x8*)(Bs + (wn * 64 + i * 16 + l15) * 72 + ks * 32 + quad * 8);
      #pragma unroll
      for (int i = 0; i < 4; i++)
        #pragma unroll
        for (int j = 0; j < 4; j++)
          acc[i][j] = __builtin_amdgcn_mfma_f32_16x16x32_bf16(af[i], bfr[j], acc[i][j], 0, 0, 0);
    }
  }
  const int b = row0 >> 11;
  float va[4], qb[4];
  #pragma unroll
  for (int j = 0; j < 4; j++) {
    int jg = j0 + wn * 64 + j * 16 + l15;
    va[j] = Va[jg];
    qb[j] = qW[b * 1024 + jg];
  }
  #pragma unroll
  for (int i = 0; i < 4; i++)
    #pragma unroll
    for (int r = 0; r < 4; r++) {
      float s = 0.f;
      #pragma unroll
      for (int j = 0; j < 4; j++) s += va[j] * fast_tanh(acc[i][j][r] + qb[j]);
      s += __shfl_xor(s, 1);
      s += __shfl_xor(s, 2);
      s += __shfl_xor(s, 4);
      s += __shfl_xor(s, 8);
      if (l15 == 0) atomicAdd(&scores[row0 + wm * 64 + i * 16 + quad * 4 + r], s);
    }
}

// ---- softmax over S=2048 per batch -> weights ----
__global__ __launch_bounds__(256) void k_softmax(const float* __restrict__ scores,
                                                 float* __restrict__ wout) {
  const int b = blockIdx.x, t = threadIdx.x;
  const int lane = t & 63, w = t >> 6;
  __shared__ float red[4];
  float v[8];
  float mx = -1e30f;
  #pragma unroll
  for (int i = 0; i < 8; i++) {
    v[i] = scores[b * 2048 + i * 256 + t];
    mx = fmaxf(mx, v[i]);
  }
  #pragma unroll
  for (int off = 1; off < 64; off <<= 1) mx = fmaxf(mx, __shfl_xor(mx, off));
  if (lane == 0) red[w] = mx;
  __syncthreads();
  mx = fmaxf(fmaxf(red[0], red[1]), fmaxf(red[2], red[3]));
  float sum = 0.f;
  #pragma unroll
  for (int i = 0; i < 8; i++) {
    v[i] = __expf(v[i] - mx);
    sum += v[i];
  }
  #pragma unroll
  for (int off = 1; off < 64; off <<= 1) sum += __shfl_xor(sum, off);
  __syncthreads();
  if (lane == 0) red[w] = sum;
  __syncthreads();
  sum = red[0] + red[1] + red[2] + red[3];
  float inv = 1.0f / sum;
  #pragma unroll
  for (int i = 0; i < 8; i++) wout[b * 2048 + i * 256 + t] = v[i] * inv;
}

// ---- context[b][d] = sum_s w[b][s]*keys[b][s][d]  (fp32 keys, HBM-bound) ----
__global__ __launch_bounds__(256) void k_context(const float* __restrict__ keys,
                                                 const float* __restrict__ wts,
                                                 float* __restrict__ ctx) {
  const int sc = blockIdx.x;   // 0..31 (64 s each)
  const int b  = blockIdx.y;   // 0..31
  const int t  = threadIdx.x;
  __shared__ float wl[64];
  if (t < 64) wl[t] = wts[b * 2048 + sc * 64 + t];
  __syncthreads();
  const float4* kp = (const float4*)(keys + ((size_t)(b * 2048 + sc * 64) << 10)) + t;
  float4 a = {0.f, 0.f, 0.f, 0.f};
  #pragma unroll 8
  for (int s = 0; s < 64; ++s) {
    float4 kv = kp[s * 256];
    float wv = wl[s];
    a.x += wv * kv.x; a.y += wv * kv.y; a.z += wv * kv.z; a.w += wv * kv.w;
  }
  float* o = ctx + b * 1024 + t * 4;
  atomicAdd(o + 0, a.x);
  atomicAdd(o + 1, a.y);
  atomicAdd(o + 2, a.z);
  atomicAdd(o + 3, a.w);
}

extern "C" void kernel_launch(void* const* d_in, const int* in_sizes, int n_in,
                              void* d_out, int out_size, void* d_ws, size_t ws_size,
                              hipStream_t stream) {
  const float* query = (const float*)d_in[0];
  const float* keys  = (const float*)d_in[1];
  const float* Wa_w  = (const float*)d_in[2];
  const float* Wa_b  = (const float*)d_in[3];
  const float* Ua_w  = (const float*)d_in[4];
  const float* Ua_b  = (const float*)d_in[5];
  const float* Va_w  = (const float*)d_in[6];
  // d_in[7] = Va_b: unused (softmax shift-invariance)

  // ws layout: scores[65536] f32 | qW[32768] f32 | Uab[1M] bf16 | keys16[64M] bf16
  float* scores = (float*)d_ws;
  float* qW     = scores + 65536;
  unsigned short* Uab    = (unsigned short*)(qW + 32768);
  unsigned short* keys16 = Uab + 1024 * 1024;
  const size_t NEED_A = 2490368ull + 134217728ull;

  float* ctx = (float*)d_out;        // context: 32*1024
  float* wts = ctx + 32768;          // weights: 32*2048

  hipMemsetAsync(scores, 0, 65536 * sizeof(float), stream);
  hipMemsetAsync(ctx, 0, 32768 * sizeof(float), stream);

  k_cvt<<<512, 256, 0, stream>>>((const float4*)Ua_w, (uint4*)Uab);
  k_qw<<<dim3(32, 32), 256, 0, stream>>>(query, Wa_w, Wa_b, Ua_b, qW);

  if (ws_size >= NEED_A) {
    k_cvt<<<32768, 256, 0, stream>>>((const float4*)keys, (uint4*)keys16);
    k_score2<<<dim3(8, 512), 256, 0, stream>>>(keys16, Uab, qW, Va_w, scores);
  } else {
    k_score1<<<dim3(8, 512), 256, 0, stream>>>(keys, Uab, qW, Va_w, scores);
  }

  k_softmax<<<32, 256, 0, stream>>>(scores, wts);
  k_context<<<dim3(32, 32), 256, 0, stream>>>(keys, wts, ctx);
}

// Round 3
// 591.948 us; speedup vs baseline: 1.4408x; 1.0516x over previous
//
#include <hip/hip_runtime.h>
#include <hip/hip_bf16.h>

// BahdanauAttention: B=32, S=2048, H=512, D2=1024
// R3: XCD-swizzled score grid (j-siblings share one XCD's L2), fused cvt,
// ctx-zero folded into softmax. ws layout identical to R2 (proven to fit).

typedef __attribute__((ext_vector_type(8))) short bf16x8;
typedef __attribute__((ext_vector_type(4))) float f32x4;

__device__ __forceinline__ unsigned pk_bf16(float x, float y) {
  union { __hip_bfloat162 h; unsigned u; } c;
  c.h = __float22bfloat162_rn(make_float2(x, y));
  return c.u;
}

__device__ __forceinline__ float fast_tanh(float x) {
  float e = __expf(2.0f * x);
  return 1.0f - 2.0f / (e + 1.0f);
}

// async global->LDS, 16B per lane; LDS dest = wave-uniform base + lane*16
typedef const __attribute__((address_space(1))) void* gas_t;
typedef __attribute__((address_space(3))) void* las_t;
__device__ __forceinline__ void ld_lds16(const void* g, void* l) {
  __builtin_amdgcn_global_load_lds((gas_t)g, (las_t)l, 16, 0, 0);
}

// ---- fused fp32->bf16 convert: Ua (262144 f4) then keys (16777216 f4) ----
// one float4/thread read, uint2 write: fully coalesced both sides.
__global__ __launch_bounds__(256) void k_cvt_all(const float4* __restrict__ keys,
                                                 const float4* __restrict__ ua,
                                                 uint2* __restrict__ keys16,
                                                 uint2* __restrict__ ua16) {
  size_t i = (size_t)blockIdx.x * 256 + threadIdx.x;
  const float4* src;
  uint2* dst;
  size_t idx;
  if (i < 262144) { src = ua; dst = ua16; idx = i; }        // block-uniform branch
  else            { src = keys; dst = keys16; idx = i - 262144; }
  float4 v = src[idx];
  uint2 o;
  o.x = pk_bf16(v.x, v.y);
  o.y = pk_bf16(v.z, v.w);
  dst[idx] = o;
}

// ---- qW[b][j] = q_cat[b]·Wa_w[j] + Wa_b[j] + Ua_b[j] ----
__global__ __launch_bounds__(256) void k_qw(const float* __restrict__ query,
                                            const float* __restrict__ Wa_w,
                                            const float* __restrict__ Wa_b,
                                            const float* __restrict__ Ua_b,
                                            float* __restrict__ qW) {
  const int jc = blockIdx.x, b = blockIdx.y, t = threadIdx.x;
  __shared__ float4 qloc[256];
  {
    // q_cat = concat(query[b,1,:], query[b,3,:]); query is (B,4,512)
    const float* base = (t < 128) ? (query + b * 2048 + 512) : (query + b * 2048 + 1536 - 512);
    qloc[t] = *(const float4*)(base + t * 4);
  }
  __syncthreads();
  const int jl = t >> 3, ks = t & 7;
  const int j = jc * 32 + jl;
  const float* wrow = Wa_w + j * 1024;
  float s = 0.f;
  #pragma unroll
  for (int i = 0; i < 32; ++i) {
    float4 wv = *(const float4*)(wrow + i * 32 + ks * 4);
    float4 q4 = qloc[i * 8 + ks];
    s += wv.x * q4.x + wv.y * q4.y + wv.z * q4.z + wv.w * q4.w;
  }
  s += __shfl_xor(s, 1);
  s += __shfl_xor(s, 2);
  s += __shfl_xor(s, 4);
  if (ks == 0) qW[b * 1024 + j] = s + Wa_b[j] + Ua_b[j];
}

// ---- PATH A score: keys16(bf16) @ Uab^T -> tanh -> ·Va -> scores (atomic) ----
// 128x128 tile, BK=64, global_load_lds staging, XOR-swizzled unpadded LDS.
// 1D grid 4096, XCD swizzle: h&7 selects XCD (dispatch %8); rblk%8 == h&7 so
// all 8 jblk siblings of one row-block run on ONE XCD -> keys slice L2-resident.
__global__ __launch_bounds__(256) void k_score2(const unsigned short* __restrict__ keys16,
                                                const unsigned short* __restrict__ Uab,
                                                const float* __restrict__ qW,
                                                const float* __restrict__ Va,
                                                float* __restrict__ scores) {
  __shared__ __align__(16) unsigned short As[128 * 64];  // 16 KB
  __shared__ __align__(16) unsigned short Bs[128 * 64];  // 16 KB
  const int h = blockIdx.x;
  const int x = h & 7, g = h >> 3;
  const int jblk = g & 7;                    // 0..7
  const int rblk = x + ((g >> 3) << 3);      // 0..511, rblk%8 == h&7 (XCD pin)
  const int t = threadIdx.x;
  const int lane = t & 63, w = t >> 6;
  const int wm = w >> 1, wn = w & 1;
  const int l15 = lane & 15, quad = lane >> 4;
  const int row0 = rblk * 128, j0 = jblk * 128;
  // staging geometry: chunk = 1KB = 8 rows x 128B; lane -> (row lr, 16B slot)
  const int lr = lane >> 3;                 // row-in-chunk 0..7
  const int sg = (lane & 7) ^ lr;           // swizzled global 16B-slot index

  f32x4 acc[4][4];
  #pragma unroll
  for (int i = 0; i < 4; i++)
    #pragma unroll
    for (int j = 0; j < 4; j++) acc[i][j] = (f32x4){0.f, 0.f, 0.f, 0.f};

  const int rb = l15 & 7;   // frag-row & 7
  const int aoff = (wm * 64 + l15) * 64;
  const int boff = (wn * 64 + l15) * 64;

  // incremental global pointers (advance 64 bf16 = 128B per iter)
  const unsigned short* ga = keys16 + (size_t)(row0 + (w * 4) * 8 + lr) * 1024 + sg * 8;
  const unsigned short* gb = Uab + (size_t)(j0 + (w * 4) * 8 + lr) * 1024 + sg * 8;

  for (int k0 = 0; k0 < 1024; k0 += 64) {
    if (k0) __syncthreads();   // prior ds_reads done before overwrite
    #pragma unroll
    for (int i = 0; i < 4; ++i) {
      const int c = w * 4 + i;
      ld_lds16(ga + (size_t)i * 8 * 1024 + k0, As + c * 512);
      ld_lds16(gb + (size_t)i * 8 * 1024 + k0, Bs + c * 512);
    }
    __syncthreads();           // drains vmcnt(0): tiles resident
    #pragma unroll
    for (int ks = 0; ks < 2; ++ks) {
      const int xf = ((ks * 4 + quad) ^ rb) * 8;   // swizzled frag slot
      bf16x8 af[4], bfr[4];
      #pragma unroll
      for (int i = 0; i < 4; i++) af[i] = *(const bf16x8*)(As + aoff + i * 1024 + xf);
      #pragma unroll
      for (int i = 0; i < 4; i++) bfr[i] = *(const bf16x8*)(Bs + boff + i * 1024 + xf);
      #pragma unroll
      for (int i = 0; i < 4; i++)
        #pragma unroll
        for (int j = 0; j < 4; j++)
          acc[i][j] = __builtin_amdgcn_mfma_f32_16x16x32_bf16(af[i], bfr[j], acc[i][j], 0, 0, 0);
    }
  }

  // epilogue: scores[r] += sum_j Va[j]*tanh(acc + qW[b][j]); Va_b dropped
  const int b = row0 >> 11;
  float va[4], qb[4];
  #pragma unroll
  for (int j = 0; j < 4; j++) {
    int jg = j0 + wn * 64 + j * 16 + l15;
    va[j] = Va[jg];
    qb[j] = qW[b * 1024 + jg];
  }
  #pragma unroll
  for (int i = 0; i < 4; i++) {
    #pragma unroll
    for (int r = 0; r < 4; r++) {
      float s = 0.f;
      #pragma unroll
      for (int j = 0; j < 4; j++)
        s += va[j] * fast_tanh(acc[i][j][r] + qb[j]);
      s += __shfl_xor(s, 1);
      s += __shfl_xor(s, 2);
      s += __shfl_xor(s, 4);
      s += __shfl_xor(s, 8);
      if (l15 == 0) {
        int rg = row0 + wm * 64 + i * 16 + quad * 4 + r;   // C/D: row = quad*4+reg
        atomicAdd(&scores[rg], s);
      }
    }
  }
}

// ---- FALLBACK score (fp32 keys in-kernel cvt) ----
__global__ __launch_bounds__(256) void k_score1(const float* __restrict__ keys,
                                                const unsigned short* __restrict__ Uab,
                                                const float* __restrict__ qW,
                                                const float* __restrict__ Va,
                                                float* __restrict__ scores) {
  __shared__ __align__(16) unsigned short As[128 * 72];
  __shared__ __align__(16) unsigned short Bs[128 * 72];
  const int jblk = blockIdx.x, rblk = blockIdx.y;
  const int t = threadIdx.x;
  const int lane = t & 63, w = t >> 6;
  const int wm = w >> 1, wn = w & 1;
  const int l15 = lane & 15, quad = lane >> 4;
  const int row0 = rblk * 128, j0 = jblk * 128;
  f32x4 acc[4][4];
  #pragma unroll
  for (int i = 0; i < 4; i++)
    #pragma unroll
    for (int j = 0; j < 4; j++) acc[i][j] = (f32x4){0.f, 0.f, 0.f, 0.f};
  for (int k0 = 0; k0 < 1024; k0 += 64) {
    __syncthreads();
    #pragma unroll
    for (int i = 0; i < 8; ++i) {
      int c = i * 256 + t, m = c >> 4, f4 = c & 15;
      float4 v = *(const float4*)(keys + (size_t)(row0 + m) * 1024 + k0 + f4 * 4);
      uint2 p;
      p.x = pk_bf16(v.x, v.y);
      p.y = pk_bf16(v.z, v.w);
      *(uint2*)(As + m * 72 + f4 * 4) = p;
    }
    #pragma unroll
    for (int i = 0; i < 4; ++i) {
      int c = i * 256 + t, j = c >> 3, k8 = c & 7;
      *(uint4*)(Bs + j * 72 + k8 * 8) = *(const uint4*)(Uab + (size_t)(j0 + j) * 1024 + k0 + k8 * 8);
    }
    __syncthreads();
    #pragma unroll
    for (int ks = 0; ks < 2; ++ks) {
      bf16x8 af[4], bfr[4];
      #pragma unroll
      for (int i = 0; i < 4; i++)
        af[i] = *(const bf16x8*)(As + (wm * 64 + i * 16 + l15) * 72 + ks * 32 + quad * 8);
      #pragma unroll
      for (int i = 0; i < 4; i++)
        bfr[i] = *(const bf16x8*)(Bs + (wn * 64 + i * 16 + l15) * 72 + ks * 32 + quad * 8);
      #pragma unroll
      for (int i = 0; i < 4; i++)
        #pragma unroll
        for (int j = 0; j < 4; j++)
          acc[i][j] = __builtin_amdgcn_mfma_f32_16x16x32_bf16(af[i], bfr[j], acc[i][j], 0, 0, 0);
    }
  }
  const int b = row0 >> 11;
  float va[4], qb[4];
  #pragma unroll
  for (int j = 0; j < 4; j++) {
    int jg = j0 + wn * 64 + j * 16 + l15;
    va[j] = Va[jg];
    qb[j] = qW[b * 1024 + jg];
  }
  #pragma unroll
  for (int i = 0; i < 4; i++)
    #pragma unroll
    for (int r = 0; r < 4; r++) {
      float s = 0.f;
      #pragma unroll
      for (int j = 0; j < 4; j++) s += va[j] * fast_tanh(acc[i][j][r] + qb[j]);
      s += __shfl_xor(s, 1);
      s += __shfl_xor(s, 2);
      s += __shfl_xor(s, 4);
      s += __shfl_xor(s, 8);
      if (l15 == 0) atomicAdd(&scores[row0 + wm * 64 + i * 16 + quad * 4 + r], s);
    }
}

// ---- softmax over S=2048 per batch -> weights; also zero ctx[b] for k_context ----
__global__ __launch_bounds__(256) void k_softmax(const float* __restrict__ scores,
                                                 float* __restrict__ wout,
                                                 float* __restrict__ ctx) {
  const int b = blockIdx.x, t = threadIdx.x;
  const int lane = t & 63, w = t >> 6;
  // zero the atomic target for k_context (runs strictly after on the stream)
  *(float4*)(ctx + b * 1024 + t * 4) = (float4){0.f, 0.f, 0.f, 0.f};
  __shared__ float red[4];
  float v[8];
  float mx = -1e30f;
  #pragma unroll
  for (int i = 0; i < 8; i++) {
    v[i] = scores[b * 2048 + i * 256 + t];
    mx = fmaxf(mx, v[i]);
  }
  #pragma unroll
  for (int off = 1; off < 64; off <<= 1) mx = fmaxf(mx, __shfl_xor(mx, off));
  if (lane == 0) red[w] = mx;
  __syncthreads();
  mx = fmaxf(fmaxf(red[0], red[1]), fmaxf(red[2], red[3]));
  float sum = 0.f;
  #pragma unroll
  for (int i = 0; i < 8; i++) {
    v[i] = __expf(v[i] - mx);
    sum += v[i];
  }
  #pragma unroll
  for (int off = 1; off < 64; off <<= 1) sum += __shfl_xor(sum, off);
  __syncthreads();
  if (lane == 0) red[w] = sum;
  __syncthreads();
  sum = red[0] + red[1] + red[2] + red[3];
  float inv = 1.0f / sum;
  #pragma unroll
  for (int i = 0; i < 8; i++) wout[b * 2048 + i * 256 + t] = v[i] * inv;
}

// ---- context[b][d] = sum_s w[b][s]*keys[b][s][d]  (fp32 keys, HBM-bound) ----
__global__ __launch_bounds__(256) void k_context(const float* __restrict__ keys,
                                                 const float* __restrict__ wts,
                                                 float* __restrict__ ctx) {
  const int sc = blockIdx.x;   // 0..31 (64 s each)
  const int b  = blockIdx.y;   // 0..31
  const int t  = threadIdx.x;
  __shared__ float wl[64];
  if (t < 64) wl[t] = wts[b * 2048 + sc * 64 + t];
  __syncthreads();
  const float4* kp = (const float4*)(keys + ((size_t)(b * 2048 + sc * 64) << 10)) + t;
  float4 a = {0.f, 0.f, 0.f, 0.f};
  #pragma unroll 8
  for (int s = 0; s < 64; ++s) {
    float4 kv = kp[s * 256];
    float wv = wl[s];
    a.x += wv * kv.x; a.y += wv * kv.y; a.z += wv * kv.z; a.w += wv * kv.w;
  }
  float* o = ctx + b * 1024 + t * 4;
  atomicAdd(o + 0, a.x);
  atomicAdd(o + 1, a.y);
  atomicAdd(o + 2, a.z);
  atomicAdd(o + 3, a.w);
}

extern "C" void kernel_launch(void* const* d_in, const int* in_sizes, int n_in,
                              void* d_out, int out_size, void* d_ws, size_t ws_size,
                              hipStream_t stream) {
  const float* query = (const float*)d_in[0];
  const float* keys  = (const float*)d_in[1];
  const float* Wa_w  = (const float*)d_in[2];
  const float* Wa_b  = (const float*)d_in[3];
  const float* Ua_w  = (const float*)d_in[4];
  const float* Ua_b  = (const float*)d_in[5];
  const float* Va_w  = (const float*)d_in[6];
  // d_in[7] = Va_b: unused (softmax shift-invariance)

  // ws layout (R2-proven 136.7MB): scores[65536] | qW[32768] | Uab 1M bf16 | keys16 64M bf16
  float* scores = (float*)d_ws;
  float* qW     = scores + 65536;
  unsigned short* Uab    = (unsigned short*)(qW + 32768);
  unsigned short* keys16 = Uab + 1024 * 1024;
  const size_t NEED_A = 2490368ull + 134217728ull;

  float* ctx = (float*)d_out;        // context: 32*1024
  float* wts = ctx + 32768;          // weights: 32*2048

  hipMemsetAsync(scores, 0, 65536 * sizeof(float), stream);
  k_qw<<<dim3(32, 32), 256, 0, stream>>>(query, Wa_w, Wa_b, Ua_b, qW);

  if (ws_size >= NEED_A) {
    k_cvt_all<<<66560, 256, 0, stream>>>((const float4*)keys, (const float4*)Ua_w,
                                         (uint2*)keys16, (uint2*)Uab);
    k_score2<<<4096, 256, 0, stream>>>(keys16, Uab, qW, Va_w, scores);
  } else {
    k_cvt_all<<<1024, 256, 0, stream>>>((const float4*)keys, (const float4*)Ua_w,
                                        (uint2*)keys16, (uint2*)Uab);  // Ua part only
    k_score1<<<dim3(8, 512), 256, 0, stream>>>(keys, Uab, qW, Va_w, scores);
  }

  k_softmax<<<32, 256, 0, stream>>>(scores, wts, ctx);
  k_context<<<dim3(32, 32), 256, 0, stream>>>(keys, wts, ctx);
}

// Round 4
// 578.305 us; speedup vs baseline: 1.4748x; 1.0236x over previous
//
#include <hip/hip_runtime.h>
#include <hip/hip_bf16.h>

// BahdanauAttention: B=32, S=2048, H=512, D2=1024
// R4: score2 occupancy push (launch_bounds(256,4): 144->128 regs, 3->4 waves/SIMD),
// context on bf16 keys16 (half traffic), qw+cvt+zero fused into one dispatch.

typedef __attribute__((ext_vector_type(8))) short bf16x8;
typedef __attribute__((ext_vector_type(4))) float f32x4;

__device__ __forceinline__ unsigned pk_bf16(float x, float y) {
  union { __hip_bfloat162 h; unsigned u; } c;
  c.h = __float22bfloat162_rn(make_float2(x, y));
  return c.u;
}

__device__ __forceinline__ float bf2f(short u) {
  union { unsigned u; float f; } c;
  c.u = ((unsigned)(unsigned short)u) << 16;
  return c.f;
}

__device__ __forceinline__ float fast_tanh(float x) {
  float e = __expf(2.0f * x);
  return 1.0f - 2.0f / (e + 1.0f);
}

// async global->LDS, 16B per lane; LDS dest = wave-uniform base + lane*16
typedef const __attribute__((address_space(1))) void* gas_t;
typedef __attribute__((address_space(3))) void* las_t;
__device__ __forceinline__ void ld_lds16(const void* g, void* l) {
  __builtin_amdgcn_global_load_lds((gas_t)g, (las_t)l, 16, 0, 0);
}

// ---- fused: blocks [0,1024): qW + zero scores; blocks [1024,..): fp32->bf16 cvt ----
// cvt covers Ua (262144 f4) then keys (16777216 f4); grid selects how much.
__global__ __launch_bounds__(256) void k_fused(const float* __restrict__ query,
                                               const float* __restrict__ Wa_w,
                                               const float* __restrict__ Wa_b,
                                               const float* __restrict__ Ua_b,
                                               const float4* __restrict__ keys,
                                               const float4* __restrict__ ua,
                                               float* __restrict__ qW,
                                               uint2* __restrict__ keys16,
                                               uint2* __restrict__ ua16,
                                               float* __restrict__ scores) {
  const int t = threadIdx.x;
  if (blockIdx.x >= 1024) {   // ---- cvt part ----
    size_t i = (size_t)(blockIdx.x - 1024) * 256 + t;
    const float4* src;
    uint2* dst;
    size_t idx;
    if (i < 262144) { src = ua; dst = ua16; idx = i; }   // block-uniform
    else            { src = keys; dst = keys16; idx = i - 262144; }
    float4 v = src[idx];
    uint2 o;
    o.x = pk_bf16(v.x, v.y);
    o.y = pk_bf16(v.z, v.w);
    dst[idx] = o;
    return;
  }
  // ---- qW part: qW[b][j] = q_cat[b]·Wa_w[j] + Wa_b[j] + Ua_b[j]; + zero scores ----
  if (t < 64) scores[blockIdx.x * 64 + t] = 0.f;
  const int jc = blockIdx.x >> 5, b = blockIdx.x & 31;
  __shared__ float4 qloc[256];
  {
    // q_cat = concat(query[b,1,:], query[b,3,:]); query is (B,4,512)
    const float* base = (t < 128) ? (query + b * 2048 + 512) : (query + b * 2048 + 1536 - 512);
    qloc[t] = *(const float4*)(base + t * 4);
  }
  __syncthreads();
  const int jl = t >> 3, ks = t & 7;
  const int j = jc * 32 + jl;
  const float* wrow = Wa_w + j * 1024;
  float s = 0.f;
  #pragma unroll
  for (int i = 0; i < 32; ++i) {
    float4 wv = *(const float4*)(wrow + i * 32 + ks * 4);
    float4 q4 = qloc[i * 8 + ks];
    s += wv.x * q4.x + wv.y * q4.y + wv.z * q4.z + wv.w * q4.w;
  }
  s += __shfl_xor(s, 1);
  s += __shfl_xor(s, 2);
  s += __shfl_xor(s, 4);
  if (ks == 0) qW[b * 1024 + j] = s + Wa_b[j] + Ua_b[j];
}

// ---- PATH A score: keys16(bf16) @ Uab^T -> tanh -> ·Va -> scores (atomic) ----
// 128x128 tile, BK=64, global_load_lds staging, XOR-swizzled unpadded LDS.
// XCD pin: rblk%8 == blockIdx.x&7 so all 8 jblk siblings of a row-block land
// on one XCD (keys slice L2-resident; R3: FETCH 532->87MB).
// launch_bounds(256,4): cap regs at 128 (64 acc AGPR + <=64 VGPR) -> 4 waves/SIMD.
__global__ __launch_bounds__(256, 4) void k_score2(const unsigned short* __restrict__ keys16,
                                                   const unsigned short* __restrict__ Uab,
                                                   const float* __restrict__ qW,
                                                   const float* __restrict__ Va,
                                                   float* __restrict__ scores) {
  __shared__ __align__(16) unsigned short As[128 * 64];  // 16 KB
  __shared__ __align__(16) unsigned short Bs[128 * 64];  // 16 KB
  const int h = blockIdx.x;
  const int x = h & 7, g = h >> 3;
  const int jblk = g & 7;                    // 0..7
  const int rblk = x + ((g >> 3) << 3);      // 0..511, rblk%8 == h&7 (XCD pin)
  const int t = threadIdx.x;
  const int lane = t & 63, w = t >> 6;
  const int wm = w >> 1, wn = w & 1;
  const int l15 = lane & 15, quad = lane >> 4;
  const int row0 = rblk * 128, j0 = jblk * 128;
  // staging geometry: chunk = 1KB = 8 rows x 128B; lane -> (row lr, 16B slot)
  const int lr = lane >> 3;                 // row-in-chunk 0..7
  const int sg = (lane & 7) ^ lr;           // swizzled global 16B-slot index

  f32x4 acc[4][4];
  #pragma unroll
  for (int i = 0; i < 4; i++)
    #pragma unroll
    for (int j = 0; j < 4; j++) acc[i][j] = (f32x4){0.f, 0.f, 0.f, 0.f};

  const int rb = l15 & 7;   // frag-row & 7
  const int aoff = (wm * 64 + l15) * 64;
  const int boff = (wn * 64 + l15) * 64;

  // incremental global pointers (advance 64 bf16 = 128B per iter)
  const unsigned short* ga = keys16 + (size_t)(row0 + (w * 4) * 8 + lr) * 1024 + sg * 8;
  const unsigned short* gb = Uab + (size_t)(j0 + (w * 4) * 8 + lr) * 1024 + sg * 8;

  for (int k0 = 0; k0 < 1024; k0 += 64) {
    if (k0) __syncthreads();   // prior ds_reads done before overwrite
    #pragma unroll
    for (int i = 0; i < 4; ++i) {
      const int c = w * 4 + i;
      ld_lds16(ga + (size_t)i * 8 * 1024 + k0, As + c * 512);
      ld_lds16(gb + (size_t)i * 8 * 1024 + k0, Bs + c * 512);
    }
    __syncthreads();           // drains vmcnt(0): tiles resident
    #pragma unroll
    for (int ks = 0; ks < 2; ++ks) {
      const int xf = ((ks * 4 + quad) ^ rb) * 8;   // swizzled frag slot
      // bfr x4 resident (32 VGPR), af loaded per-i: peak live ~44 VGPR
      bf16x8 bfr0 = *(const bf16x8*)(Bs + boff + 0 * 1024 + xf);
      bf16x8 bfr1 = *(const bf16x8*)(Bs + boff + 1 * 1024 + xf);
      bf16x8 bfr2 = *(const bf16x8*)(Bs + boff + 2 * 1024 + xf);
      bf16x8 bfr3 = *(const bf16x8*)(Bs + boff + 3 * 1024 + xf);
      #pragma unroll
      for (int i = 0; i < 4; i++) {
        bf16x8 af = *(const bf16x8*)(As + aoff + i * 1024 + xf);
        acc[i][0] = __builtin_amdgcn_mfma_f32_16x16x32_bf16(af, bfr0, acc[i][0], 0, 0, 0);
        acc[i][1] = __builtin_amdgcn_mfma_f32_16x16x32_bf16(af, bfr1, acc[i][1], 0, 0, 0);
        acc[i][2] = __builtin_amdgcn_mfma_f32_16x16x32_bf16(af, bfr2, acc[i][2], 0, 0, 0);
        acc[i][3] = __builtin_amdgcn_mfma_f32_16x16x32_bf16(af, bfr3, acc[i][3], 0, 0, 0);
      }
    }
  }

  // epilogue: scores[r] += sum_j Va[j]*tanh(acc + qW[b][j]); Va_b dropped
  const int b = row0 >> 11;
  float va[4], qb[4];
  #pragma unroll
  for (int j = 0; j < 4; j++) {
    int jg = j0 + wn * 64 + j * 16 + l15;
    va[j] = Va[jg];
    qb[j] = qW[b * 1024 + jg];
  }
  #pragma unroll
  for (int i = 0; i < 4; i++) {
    #pragma unroll
    for (int r = 0; r < 4; r++) {
      float s = 0.f;
      #pragma unroll
      for (int j = 0; j < 4; j++)
        s += va[j] * fast_tanh(acc[i][j][r] + qb[j]);
      s += __shfl_xor(s, 1);
      s += __shfl_xor(s, 2);
      s += __shfl_xor(s, 4);
      s += __shfl_xor(s, 8);
      if (l15 == 0) {
        int rg = row0 + wm * 64 + i * 16 + quad * 4 + r;   // C/D: row = quad*4+reg
        atomicAdd(&scores[rg], s);
      }
    }
  }
}

// ---- FALLBACK score (fp32 keys in-kernel cvt) ----
__global__ __launch_bounds__(256) void k_score1(const float* __restrict__ keys,
                                                const unsigned short* __restrict__ Uab,
                                                const float* __restrict__ qW,
                                                const float* __restrict__ Va,
                                                float* __restrict__ scores) {
  __shared__ __align__(16) unsigned short As[128 * 72];
  __shared__ __align__(16) unsigned short Bs[128 * 72];
  const int jblk = blockIdx.x, rblk = blockIdx.y;
  const int t = threadIdx.x;
  const int lane = t & 63, w = t >> 6;
  const int wm = w >> 1, wn = w & 1;
  const int l15 = lane & 15, quad = lane >> 4;
  const int row0 = rblk * 128, j0 = jblk * 128;
  f32x4 acc[4][4];
  #pragma unroll
  for (int i = 0; i < 4; i++)
    #pragma unroll
    for (int j = 0; j < 4; j++) acc[i][j] = (f32x4){0.f, 0.f, 0.f, 0.f};
  for (int k0 = 0; k0 < 1024; k0 += 64) {
    __syncthreads();
    #pragma unroll
    for (int i = 0; i < 8; ++i) {
      int c = i * 256 + t, m = c >> 4, f4 = c & 15;
      float4 v = *(const float4*)(keys + (size_t)(row0 + m) * 1024 + k0 + f4 * 4);
      uint2 p;
      p.x = pk_bf16(v.x, v.y);
      p.y = pk_bf16(v.z, v.w);
      *(uint2*)(As + m * 72 + f4 * 4) = p;
    }
    #pragma unroll
    for (int i = 0; i < 4; ++i) {
      int c = i * 256 + t, j = c >> 3, k8 = c & 7;
      *(uint4*)(Bs + j * 72 + k8 * 8) = *(const uint4*)(Uab + (size_t)(j0 + j) * 1024 + k0 + k8 * 8);
    }
    __syncthreads();
    #pragma unroll
    for (int ks = 0; ks < 2; ++ks) {
      bf16x8 af[4], bfr[4];
      #pragma unroll
      for (int i = 0; i < 4; i++)
        af[i] = *(const bf16x8*)(As + (wm * 64 + i * 16 + l15) * 72 + ks * 32 + quad * 8);
      #pragma unroll
      for (int i = 0; i < 4; i++)
        bfr[i] = *(const bf16x8*)(Bs + (wn * 64 + i * 16 + l15) * 72 + ks * 32 + quad * 8);
      #pragma unroll
      for (int i = 0; i < 4; i++)
        #pragma unroll
        for (int j = 0; j < 4; j++)
          acc[i][j] = __builtin_amdgcn_mfma_f32_16x16x32_bf16(af[i], bfr[j], acc[i][j], 0, 0, 0);
    }
  }
  const int b = row0 >> 11;
  float va[4], qb[4];
  #pragma unroll
  for (int j = 0; j < 4; j++) {
    int jg = j0 + wn * 64 + j * 16 + l15;
    va[j] = Va[jg];
    qb[j] = qW[b * 1024 + jg];
  }
  #pragma unroll
  for (int i = 0; i < 4; i++)
    #pragma unroll
    for (int r = 0; r < 4; r++) {
      float s = 0.f;
      #pragma unroll
      for (int j = 0; j < 4; j++) s += va[j] * fast_tanh(acc[i][j][r] + qb[j]);
      s += __shfl_xor(s, 1);
      s += __shfl_xor(s, 2);
      s += __shfl_xor(s, 4);
      s += __shfl_xor(s, 8);
      if (l15 == 0) atomicAdd(&scores[row0 + wm * 64 + i * 16 + quad * 4 + r], s);
    }
}

// ---- softmax over S=2048 per batch -> weights; also zero ctx[b] for k_context ----
__global__ __launch_bounds__(256) void k_softmax(const float* __restrict__ scores,
                                                 float* __restrict__ wout,
                                                 float* __restrict__ ctx) {
  const int b = blockIdx.x, t = threadIdx.x;
  const int lane = t & 63, w = t >> 6;
  *(float4*)(ctx + b * 1024 + t * 4) = (float4){0.f, 0.f, 0.f, 0.f};
  __shared__ float red[4];
  float v[8];
  float mx = -1e30f;
  #pragma unroll
  for (int i = 0; i < 8; i++) {
    v[i] = scores[b * 2048 + i * 256 + t];
    mx = fmaxf(mx, v[i]);
  }
  #pragma unroll
  for (int off = 1; off < 64; off <<= 1) mx = fmaxf(mx, __shfl_xor(mx, off));
  if (lane == 0) red[w] = mx;
  __syncthreads();
  mx = fmaxf(fmaxf(red[0], red[1]), fmaxf(red[2], red[3]));
  float sum = 0.f;
  #pragma unroll
  for (int i = 0; i < 8; i++) {
    v[i] = __expf(v[i] - mx);
    sum += v[i];
  }
  #pragma unroll
  for (int off = 1; off < 64; off <<= 1) sum += __shfl_xor(sum, off);
  __syncthreads();
  if (lane == 0) red[w] = sum;
  __syncthreads();
  sum = red[0] + red[1] + red[2] + red[3];
  float inv = 1.0f / sum;
  #pragma unroll
  for (int i = 0; i < 8; i++) wout[b * 2048 + i * 256 + t] = v[i] * inv;
}

// ---- PATH A context: ctx[b][d] = sum_s w[b][s]*keys16[b][s][d] (bf16, 128MB) ----
// 64 s-rows/block; t = (so: s-parity, tc: 8 d-cols); 16B/lane coalesced loads.
__global__ __launch_bounds__(256) void k_context2(const unsigned short* __restrict__ keys16,
                                                  const float* __restrict__ wts,
                                                  float* __restrict__ ctx) {
  const int sc = blockIdx.x;   // 0..31
  const int b  = blockIdx.y;   // 0..31
  const int t  = threadIdx.x;
  const int so = t >> 7, tc = t & 127;
  __shared__ float wl[64];
  __shared__ float ps[128 * 8];   // partial from so=1 half
  if (t < 64) wl[t] = wts[b * 2048 + sc * 64 + t];
  __syncthreads();
  const unsigned short* kp = keys16 + (size_t)(b * 2048 + sc * 64 + so) * 1024 + tc * 8;
  float a[8] = {0.f, 0.f, 0.f, 0.f, 0.f, 0.f, 0.f, 0.f};
  #pragma unroll 4
  for (int s = 0; s < 64; s += 2) {
    bf16x8 kv = *(const bf16x8*)(kp + (size_t)s * 1024);
    float wv = wl[s + so];
    #pragma unroll
    for (int i = 0; i < 8; i++) a[i] += wv * bf2f(kv[i]);
  }
  if (so == 1) {
    #pragma unroll
    for (int i = 0; i < 8; i++) ps[tc * 8 + i] = a[i];
  }
  __syncthreads();
  if (so == 0) {
    float* o = ctx + b * 1024 + tc * 8;
    #pragma unroll
    for (int i = 0; i < 8; i++) atomicAdd(o + i, a[i] + ps[tc * 8 + i]);
  }
}

// ---- FALLBACK context (fp32 keys) ----
__global__ __launch_bounds__(256) void k_context1(const float* __restrict__ keys,
                                                  const float* __restrict__ wts,
                                                  float* __restrict__ ctx) {
  const int sc = blockIdx.x;   // 0..31 (64 s each)
  const int b  = blockIdx.y;
  const int t  = threadIdx.x;
  __shared__ float wl[64];
  if (t < 64) wl[t] = wts[b * 2048 + sc * 64 + t];
  __syncthreads();
  const float4* kp = (const float4*)(keys + ((size_t)(b * 2048 + sc * 64) << 10)) + t;
  float4 a = {0.f, 0.f, 0.f, 0.f};
  #pragma unroll 8
  for (int s = 0; s < 64; ++s) {
    float4 kv = kp[s * 256];
    float wv = wl[s];
    a.x += wv * kv.x; a.y += wv * kv.y; a.z += wv * kv.z; a.w += wv * kv.w;
  }
  float* o = ctx + b * 1024 + t * 4;
  atomicAdd(o + 0, a.x);
  atomicAdd(o + 1, a.y);
  atomicAdd(o + 2, a.z);
  atomicAdd(o + 3, a.w);
}

extern "C" void kernel_launch(void* const* d_in, const int* in_sizes, int n_in,
                              void* d_out, int out_size, void* d_ws, size_t ws_size,
                              hipStream_t stream) {
  const float* query = (const float*)d_in[0];
  const float* keys  = (const float*)d_in[1];
  const float* Wa_w  = (const float*)d_in[2];
  const float* Wa_b  = (const float*)d_in[3];
  const float* Ua_w  = (const float*)d_in[4];
  const float* Ua_b  = (const float*)d_in[5];
  const float* Va_w  = (const float*)d_in[6];
  // d_in[7] = Va_b: unused (softmax shift-invariance)

  // ws layout (136.7MB): scores[65536] | qW[32768] | Uab 1M bf16 | keys16 64M bf16
  float* scores = (float*)d_ws;
  float* qW     = scores + 65536;
  unsigned short* Uab    = (unsigned short*)(qW + 32768);
  unsigned short* keys16 = Uab + 1024 * 1024;
  const size_t NEED_A = 2490368ull + 134217728ull;

  float* ctx = (float*)d_out;        // context: 32*1024
  float* wts = ctx + 32768;          // weights: 32*2048

  if (ws_size >= NEED_A) {
    k_fused<<<67584, 256, 0, stream>>>(query, Wa_w, Wa_b, Ua_b, (const float4*)keys,
                                       (const float4*)Ua_w, qW, (uint2*)keys16,
                                       (uint2*)Uab, scores);
    k_score2<<<4096, 256, 0, stream>>>(keys16, Uab, qW, Va_w, scores);
    k_softmax<<<32, 256, 0, stream>>>(scores, wts, ctx);
    k_context2<<<dim3(32, 32), 256, 0, stream>>>(keys16, wts, ctx);
  } else {
    k_fused<<<2048, 256, 0, stream>>>(query, Wa_w, Wa_b, Ua_b, (const float4*)keys,
                                      (const float4*)Ua_w, qW, (uint2*)keys16,
                                      (uint2*)Uab, scores);   // ua cvt only
    k_score1<<<dim3(8, 512), 256, 0, stream>>>(keys, Uab, qW, Va_w, scores);
    k_softmax<<<32, 256, 0, stream>>>(scores, wts, ctx);
    k_context1<<<dim3(32, 32), 256, 0, stream>>>(keys, wts, ctx);
  }
}